// Round 1
// baseline (1174.369 us; speedup 1.0000x reference)
//
#include <hip/hip_runtime.h>
#include <hip/hip_bf16.h>

#define DEV static __device__ __forceinline__

typedef __attribute__((ext_vector_type(8))) short bf16x8;
typedef __attribute__((ext_vector_type(4))) float f32x4;

constexpr int KM   = 165;          // number of monomials (deg<=3, 8 complex vars)
constexpr int IT   = 11;           // i-tiles of 16 -> 176 padded
constexpr int KS   = 6;            // k-steps of 32 -> 192 padded
constexpr int NB   = IT * KS * 64; // B-fragment slots (uint4 each) = 4224
constexpr int ROWS = 64;           // batch rows per block
constexpr int RSTR = 97;           // LDS row stride in dwords (odd -> bank balanced)

// ---------------- compile-time POWERS table (itertools.product order) ----------------
struct Pw { unsigned char p[8]; };
struct PwTab { Pw a[KM]; };
constexpr PwTab gen_powers() {
  PwTab t{};
  int idx = 0;
  for (int a0 = 0; a0 <= 3; ++a0)
  for (int a1 = 0; a1 <= 3-a0; ++a1)
  for (int a2 = 0; a2 <= 3-a0-a1; ++a2)
  for (int a3 = 0; a3 <= 3-a0-a1-a2; ++a3)
  for (int a4 = 0; a4 <= 3-a0-a1-a2-a3; ++a4)
  for (int a5 = 0; a5 <= 3-a0-a1-a2-a3-a4; ++a5)
  for (int a6 = 0; a6 <= 3-a0-a1-a2-a3-a4-a5; ++a6)
  for (int a7 = 0; a7 <= 3-a0-a1-a2-a3-a4-a5-a6; ++a7) {
    t.a[idx].p[0] = (unsigned char)a0; t.a[idx].p[1] = (unsigned char)a1;
    t.a[idx].p[2] = (unsigned char)a2; t.a[idx].p[3] = (unsigned char)a3;
    t.a[idx].p[4] = (unsigned char)a4; t.a[idx].p[5] = (unsigned char)a5;
    t.a[idx].p[6] = (unsigned char)a6; t.a[idx].p[7] = (unsigned char)a7;
    ++idx;
  }
  return t;
}
constexpr PwTab PW = gen_powers();

// ---------------- helpers ----------------
DEV unsigned int f2bf(float f) {            // RNE float -> bf16 bits
  unsigned int u = __builtin_bit_cast(unsigned int, f);
  u += 0x7fffu + ((u >> 16) & 1u);
  return u >> 16;
}
DEV unsigned int pack2(float lo, float hi) { return f2bf(lo) | (f2bf(hi) << 16); }
DEV float bfsel(unsigned int pair, int hi) {
  unsigned int v = hi ? (pair & 0xffff0000u) : (pair << 16);
  return __builtin_bit_cast(float, v);
}
DEV float softplusf(float x) { return (x > 20.f) ? x : log1pf(expf(x)); }

DEV void mono_eval(int jj, const float (&lx)[8][3], const float (&ly)[8][3],
                   float &mr, float &mi) {
  float r = 1.f, i = 0.f;
#pragma unroll
  for (int c = 0; c < 8; ++c) {
    const int pc = PW.a[jj].p[c];
    if (pc) {
      const float ar = lx[c][pc-1], ai = ly[c][pc-1];
      const float tr = r*ar - i*ai;
      i = r*ai + i*ar;
      r = tr;
    }
  }
  mr = r; mi = i;
}

union AU { unsigned int u[4]; bf16x8 v; };
union BU { uint4 u; bf16x8 v; };

// ---------------- prep: H = L L^H  -> bf16 B-operand fragments ----------------
__global__ void __launch_bounds__(256) poskahler_prep(
    const float* __restrict__ Lre, const float* __restrict__ Lim,
    uint4* __restrict__ bre, uint4* __restrict__ bim) {
  const int tid = blockIdx.x * 256 + threadIdx.x;
  if (tid >= NB) return;
  const int lane = tid & 63;
  const int it = (tid >> 6) / KS;
  const int ks = (tid >> 6) % KS;
  const int i  = it * 16 + (lane & 15);          // H row (fragment col)
  const int jb = ks * 32 + ((lane >> 4) << 3);   // H col base (fragment k-dim)
  float hre[8], him[8];
#pragma unroll
  for (int e = 0; e < 8; ++e) { hre[e] = 0.f; him[e] = 0.f; }
  if (i < KM) {
    const float di = softplusf(Lre[i*KM + i]) + 0.001f;
    for (int e = 0; e < 8; ++e) {
      const int j = jb + e;
      if (j >= KM) break;
      const float dj = softplusf(Lre[j*KM + j]) + 0.001f;
      const int kmax = (i < j) ? i : j;
      float sr = 0.f, si = 0.f;
      for (int k = 0; k <= kmax; ++k) {
        const float ar = (k < i) ? Lre[i*KM + k] : di;
        const float ai = (k < i) ? Lim[i*KM + k] : 0.f;
        const float br = (k < j) ? Lre[j*KM + k] : dj;
        const float bi = (k < j) ? Lim[j*KM + k] : 0.f;
        sr += ar*br + ai*bi;          // Re(L[i,k] * conj(L[j,k]))
        si += ai*br - ar*bi;          // Im(L[i,k] * conj(L[j,k]))
      }
      hre[e] = sr; him[e] = si;
    }
  }
  uint4 pr, pi;
  pr.x = pack2(hre[0], hre[1]); pr.y = pack2(hre[2], hre[3]);
  pr.z = pack2(hre[4], hre[5]); pr.w = pack2(hre[6], hre[7]);
  pi.x = pack2(him[0], him[1]); pi.y = pack2(him[2], him[3]);
  pi.z = pack2(him[4], him[5]); pi.w = pack2(him[6], him[7]);
  bre[tid] = pr;
  bim[tid] = pi;
}

// ---------------- main: monomials -> complex MFMA quad form -> log ----------------
__global__ void poskahler_main(
    const float* __restrict__ q,
    const uint4* __restrict__ bre, const uint4* __restrict__ bim,
    float* __restrict__ out) {
  __shared__ unsigned int Xl[ROWS * RSTR];   // Re(monomials), bf16 pairs per dword
  __shared__ unsigned int Yl[ROWS * RSTR];   // Im(monomials)
  __shared__ float qpart[2][ROWS];

  const int t    = threadIdx.x;
  const int lane = t & 63;
  const int wv   = t >> 6;                   // 2 waves per block
  const int bbase = blockIdx.x * ROWS;

  // ---- monomial generation: each wave writes one j-half for all 64 rows ----
  {
    const float* qr = q + (size_t)(bbase + lane) * 16;
    const float4 q0 = ((const float4*)qr)[0];
    const float4 q1 = ((const float4*)qr)[1];
    const float4 q2 = ((const float4*)qr)[2];
    const float4 q3 = ((const float4*)qr)[3];
    const float xs[8] = {q0.x,q0.y,q0.z,q0.w,q1.x,q1.y,q1.z,q1.w};
    const float ys[8] = {q2.x,q2.y,q2.z,q2.w,q3.x,q3.y,q3.z,q3.w};
    float lx[8][3], ly[8][3];
#pragma unroll
    for (int c = 0; c < 8; ++c) {
      const float xr = xs[c], yi = ys[c];
      lx[c][0] = xr;             ly[c][0] = yi;
      lx[c][1] = xr*xr - yi*yi;  ly[c][1] = 2.f*xr*yi;
      lx[c][2] = lx[c][1]*xr - ly[c][1]*yi;
      ly[c][2] = lx[c][1]*yi + ly[c][1]*xr;
    }
    const unsigned int rb = (unsigned int)lane * RSTR;
    if (wv == 0) {
#pragma unroll
      for (int d = 0; d < 48; ++d) {
        float r0, i0, r1, i1;
        mono_eval(2*d,     lx, ly, r0, i0);
        mono_eval(2*d + 1, lx, ly, r1, i1);
        Xl[rb + d] = pack2(r0, r1);
        Yl[rb + d] = pack2(i0, i1);
      }
    } else {
#pragma unroll
      for (int d = 48; d < 96; ++d) {
        float r0 = 0.f, i0 = 0.f, r1 = 0.f, i1 = 0.f;
        if (2*d < KM)     mono_eval(2*d,     lx, ly, r0, i0);
        if (2*d + 1 < KM) mono_eval(2*d + 1, lx, ly, r1, i1);
        Xl[rb + d] = pack2(r0, r1);
        Yl[rb + d] = pack2(i0, i1);
      }
    }
  }
  __syncthreads();

  // ---- complex GEMM: W = H z, fused  quad = Re(z^H W) ----
  const int g    = lane >> 4;
  const int r15  = lane & 15;
  const int itlo = wv * 6;                  // wave0: it 0..5, wave1: it 6..10

  f32x4 aRe[6][4], aIm[6][4];
#pragma unroll
  for (int ii = 0; ii < 6; ++ii)
#pragma unroll
    for (int mf = 0; mf < 4; ++mf) {
      aRe[ii][mf] = (f32x4){0.f,0.f,0.f,0.f};
      aIm[ii][mf] = (f32x4){0.f,0.f,0.f,0.f};
    }

  for (int ks = 0; ks < KS; ++ks) {
    AU xf[4], yf[4];
#pragma unroll
    for (int mf = 0; mf < 4; ++mf) {
      const unsigned int base = (unsigned int)(mf*16 + r15) * RSTR + 16*ks + 4*g;
#pragma unroll
      for (int d2 = 0; d2 < 4; ++d2) {
        xf[mf].u[d2] = Xl[base + d2];
        yf[mf].u[d2] = Yl[base + d2];
      }
    }
#pragma unroll
    for (int ii = 0; ii < 6; ++ii) {
      const int it = itlo + ii;
      if (it < IT) {
        const int fs = (it*KS + ks)*64 + lane;
        BU ubr, ubi, ubn;
        ubr.u = bre[fs];
        ubi.u = bim[fs];
        ubn.u.x = ubi.u.x ^ 0x80008000u; ubn.u.y = ubi.u.y ^ 0x80008000u;
        ubn.u.z = ubi.u.z ^ 0x80008000u; ubn.u.w = ubi.u.w ^ 0x80008000u;
#pragma unroll
        for (int mf = 0; mf < 4; ++mf) {
          // Wre = X*Hre - Y*Him ; Wim = X*Him + Y*Hre
          aRe[ii][mf] = __builtin_amdgcn_mfma_f32_16x16x32_bf16(xf[mf].v, ubr.v, aRe[ii][mf], 0, 0, 0);
          aRe[ii][mf] = __builtin_amdgcn_mfma_f32_16x16x32_bf16(yf[mf].v, ubn.v, aRe[ii][mf], 0, 0, 0);
          aIm[ii][mf] = __builtin_amdgcn_mfma_f32_16x16x32_bf16(xf[mf].v, ubi.v, aIm[ii][mf], 0, 0, 0);
          aIm[ii][mf] = __builtin_amdgcn_mfma_f32_16x16x32_bf16(yf[mf].v, ubr.v, aIm[ii][mf], 0, 0, 0);
        }
      }
    }
  }

  // ---- epilogue: quad_b += x*Wre + y*Wim, reduce over i ----
  float p[4][4];
#pragma unroll
  for (int mf = 0; mf < 4; ++mf)
#pragma unroll
    for (int rr = 0; rr < 4; ++rr) p[mf][rr] = 0.f;

#pragma unroll
  for (int ii = 0; ii < 6; ++ii) {
    const int it = itlo + ii;
    if (it < IT) {
      const int dwi  = it*8 + (r15 >> 1);   // dword index of i = it*16 + r15
      const int hsel = r15 & 1;
#pragma unroll
      for (int mf = 0; mf < 4; ++mf) {
#pragma unroll
        for (int rr = 0; rr < 4; ++rr) {
          const int brow = mf*16 + 4*g + rr;          // D row = batch row
          const unsigned int px = Xl[(unsigned int)brow*RSTR + dwi];
          const unsigned int py = Yl[(unsigned int)brow*RSTR + dwi];
          p[mf][rr] += bfsel(px, hsel) * aRe[ii][mf][rr]
                     + bfsel(py, hsel) * aIm[ii][mf][rr];
        }
      }
    }
  }

#pragma unroll
  for (int mf = 0; mf < 4; ++mf)
#pragma unroll
    for (int rr = 0; rr < 4; ++rr) {
      float v = p[mf][rr];
      v += __shfl_xor(v, 1);
      v += __shfl_xor(v, 2);
      v += __shfl_xor(v, 4);
      v += __shfl_xor(v, 8);
      p[mf][rr] = v;
    }

  if (r15 == 0) {
#pragma unroll
    for (int mf = 0; mf < 4; ++mf)
#pragma unroll
      for (int rr = 0; rr < 4; ++rr)
        qpart[wv][mf*16 + 4*g + rr] = p[mf][rr];
  }
  __syncthreads();
  if (t < ROWS) {
    const float quad = qpart[0][t] + qpart[1][t];
    out[bbase + t] = logf(quad + 1e-12f);
  }
}

// ---------------- host ----------------
extern "C" void kernel_launch(void* const* d_in, const int* in_sizes, int n_in,
                              void* d_out, int out_size, void* d_ws, size_t ws_size,
                              hipStream_t stream) {
  const float* q   = (const float*)d_in[0];
  const float* Lre = (const float*)d_in[1];
  const float* Lim = (const float*)d_in[2];
  float* out = (float*)d_out;
  uint4* bre = (uint4*)d_ws;
  uint4* bim = bre + NB;
  const int B = in_sizes[0] / 16;
  poskahler_prep<<<(NB + 255)/256, 256, 0, stream>>>(Lre, Lim, bre, bim);
  poskahler_main<<<B / ROWS, 128, 0, stream>>>(q, bre, bim, out);
}

// Round 2
// 797.361 us; speedup vs baseline: 1.4728x; 1.4728x over previous
//
#include <hip/hip_runtime.h>
#include <hip/hip_bf16.h>

#define DEV static __device__ __forceinline__

typedef __attribute__((ext_vector_type(8))) short bf16x8;
typedef __attribute__((ext_vector_type(4))) float f32x4;

constexpr int KM   = 165;          // number of monomials (deg<=3, 8 complex vars)
constexpr int IT   = 11;           // live i-tiles of 16 (165 -> 176)
constexpr int ITP  = 12;           // padded i-tiles (zero tile at it=11 -> branch-free waves)
constexpr int KS   = 6;            // k-steps of 32 -> 192 padded
constexpr int NB   = ITP * KS * 64; // B-fragment slots (uint4 each) = 4608
constexpr int ROWS = 64;           // batch rows per block
constexpr int RSTR = 97;           // LDS row stride in dwords (odd -> bank balanced)

// ---------------- compile-time POWERS table (itertools.product order) ----------------
struct Pw { unsigned char p[8]; };
struct PwTab { Pw a[KM]; };
constexpr PwTab gen_powers() {
  PwTab t{};
  int idx = 0;
  for (int a0 = 0; a0 <= 3; ++a0)
  for (int a1 = 0; a1 <= 3-a0; ++a1)
  for (int a2 = 0; a2 <= 3-a0-a1; ++a2)
  for (int a3 = 0; a3 <= 3-a0-a1-a2; ++a3)
  for (int a4 = 0; a4 <= 3-a0-a1-a2-a3; ++a4)
  for (int a5 = 0; a5 <= 3-a0-a1-a2-a3-a4; ++a5)
  for (int a6 = 0; a6 <= 3-a0-a1-a2-a3-a4-a5; ++a6)
  for (int a7 = 0; a7 <= 3-a0-a1-a2-a3-a4-a5-a6; ++a7) {
    t.a[idx].p[0] = (unsigned char)a0; t.a[idx].p[1] = (unsigned char)a1;
    t.a[idx].p[2] = (unsigned char)a2; t.a[idx].p[3] = (unsigned char)a3;
    t.a[idx].p[4] = (unsigned char)a4; t.a[idx].p[5] = (unsigned char)a5;
    t.a[idx].p[6] = (unsigned char)a6; t.a[idx].p[7] = (unsigned char)a7;
    ++idx;
  }
  return t;
}
constexpr PwTab PW = gen_powers();

// ---------------- helpers ----------------
DEV unsigned int f2bf(float f) {            // RNE float -> bf16 bits
  unsigned int u = __builtin_bit_cast(unsigned int, f);
  u += 0x7fffu + ((u >> 16) & 1u);
  return u >> 16;
}
DEV unsigned int pack2(float lo, float hi) { return f2bf(lo) | (f2bf(hi) << 16); }
DEV float bfsel(unsigned int pair, int hi) {
  unsigned int v = hi ? (pair & 0xffff0000u) : (pair << 16);
  return __builtin_bit_cast(float, v);
}
DEV float softplusf(float x) { return (x > 20.f) ? x : log1pf(expf(x)); }

DEV void mono_eval(int jj, const float (&lx)[8][3], const float (&ly)[8][3],
                   float &mr, float &mi) {
  float r = 1.f, i = 0.f;
#pragma unroll
  for (int c = 0; c < 8; ++c) {
    const int pc = PW.a[jj].p[c];
    if (pc) {
      const float ar = lx[c][pc-1], ai = ly[c][pc-1];
      const float tr = r*ar - i*ai;
      i = r*ai + i*ar;
      r = tr;
    }
  }
  mr = r; mi = i;
}

union AU { unsigned int u[4]; bf16x8 v; };
union BU { uint4 u; bf16x8 v; };

// ---------------- prep: H = L L^H  -> bf16 B-operand fragments ----------------
__global__ void __launch_bounds__(256) poskahler_prep(
    const float* __restrict__ Lre, const float* __restrict__ Lim,
    uint4* __restrict__ bre, uint4* __restrict__ bim) {
  const int tid = blockIdx.x * 256 + threadIdx.x;
  if (tid >= NB) return;
  const int lane = tid & 63;
  const int it = (tid >> 6) / KS;
  const int ks = (tid >> 6) % KS;
  const int i  = it * 16 + (lane & 15);          // H row (fragment col)
  const int jb = ks * 32 + ((lane >> 4) << 3);   // H col base (fragment k-dim)
  float hre[8], him[8];
#pragma unroll
  for (int e = 0; e < 8; ++e) { hre[e] = 0.f; him[e] = 0.f; }
  if (i < KM) {
    const float di = softplusf(Lre[i*KM + i]) + 0.001f;
    for (int e = 0; e < 8; ++e) {
      const int j = jb + e;
      if (j >= KM) break;
      const float dj = softplusf(Lre[j*KM + j]) + 0.001f;
      const int kmax = (i < j) ? i : j;
      float sr = 0.f, si = 0.f;
      for (int k = 0; k <= kmax; ++k) {
        const float ar = (k < i) ? Lre[i*KM + k] : di;
        const float ai = (k < i) ? Lim[i*KM + k] : 0.f;
        const float br = (k < j) ? Lre[j*KM + k] : dj;
        const float bi = (k < j) ? Lim[j*KM + k] : 0.f;
        sr += ar*br + ai*bi;          // Re(L[i,k] * conj(L[j,k]))
        si += ai*br - ar*bi;          // Im(L[i,k] * conj(L[j,k]))
      }
      hre[e] = sr; him[e] = si;
    }
  }
  uint4 pr, pi;
  pr.x = pack2(hre[0], hre[1]); pr.y = pack2(hre[2], hre[3]);
  pr.z = pack2(hre[4], hre[5]); pr.w = pack2(hre[6], hre[7]);
  pi.x = pack2(him[0], him[1]); pi.y = pack2(him[2], him[3]);
  pi.z = pack2(him[4], him[5]); pi.w = pack2(him[6], him[7]);
  bre[tid] = pr;
  bim[tid] = pi;
}

// ---------------- main: monomials -> complex MFMA quad form -> log ----------------
__global__ void __launch_bounds__(128, 2) poskahler_main(
    const float* __restrict__ q,
    const uint4* __restrict__ bre, const uint4* __restrict__ bim,
    float* __restrict__ out) {
  __shared__ unsigned int Xl[ROWS * RSTR];   // Re(monomials), bf16 pairs per dword
  __shared__ unsigned int Yl[ROWS * RSTR];   // Im(monomials)
  __shared__ float qpart[2][ROWS];

  const int t    = threadIdx.x;
  const int lane = t & 63;
  const int wv   = t >> 6;                   // 2 waves per block
  const int bbase = blockIdx.x * ROWS;

  // ---- monomial generation: each wave writes one j-half for all 64 rows ----
  {
    const float* qr = q + (size_t)(bbase + lane) * 16;
    const float4 q0 = ((const float4*)qr)[0];
    const float4 q1 = ((const float4*)qr)[1];
    const float4 q2 = ((const float4*)qr)[2];
    const float4 q3 = ((const float4*)qr)[3];
    const float xs[8] = {q0.x,q0.y,q0.z,q0.w,q1.x,q1.y,q1.z,q1.w};
    const float ys[8] = {q2.x,q2.y,q2.z,q2.w,q3.x,q3.y,q3.z,q3.w};
    float lx[8][3], ly[8][3];
#pragma unroll
    for (int c = 0; c < 8; ++c) {
      const float xr = xs[c], yi = ys[c];
      lx[c][0] = xr;             ly[c][0] = yi;
      lx[c][1] = xr*xr - yi*yi;  ly[c][1] = 2.f*xr*yi;
      lx[c][2] = lx[c][1]*xr - ly[c][1]*yi;
      ly[c][2] = lx[c][1]*yi + ly[c][1]*xr;
    }
    const unsigned int rb = (unsigned int)lane * RSTR;
    if (wv == 0) {
#pragma unroll
      for (int d = 0; d < 48; ++d) {
        float r0, i0, r1, i1;
        mono_eval(2*d,     lx, ly, r0, i0);
        mono_eval(2*d + 1, lx, ly, r1, i1);
        Xl[rb + d] = pack2(r0, r1);
        Yl[rb + d] = pack2(i0, i1);
      }
    } else {
#pragma unroll
      for (int d = 48; d < 96; ++d) {
        float r0 = 0.f, i0 = 0.f, r1 = 0.f, i1 = 0.f;
        if (2*d < KM)     mono_eval(2*d,     lx, ly, r0, i0);
        if (2*d + 1 < KM) mono_eval(2*d + 1, lx, ly, r1, i1);
        Xl[rb + d] = pack2(r0, r1);
        Yl[rb + d] = pack2(i0, i1);
      }
    }
  }
  __syncthreads();

  // ---- complex GEMM, i-tiles in groups of 3 with fused epilogue ----
  const int g    = lane >> 4;
  const int r15  = lane & 15;
  const int itbase = wv * 6;                // wave0: it 0..5, wave1: it 6..11 (11 = zero pad)

  float p[4][4];
#pragma unroll
  for (int mf = 0; mf < 4; ++mf)
#pragma unroll
    for (int rr = 0; rr < 4; ++rr) p[mf][rr] = 0.f;

  for (int grp = 0; grp < 2; ++grp) {
    const int it0 = itbase + grp * 3;

    f32x4 aRe[3][4], aIm[3][4];
#pragma unroll
    for (int ii = 0; ii < 3; ++ii)
#pragma unroll
      for (int mf = 0; mf < 4; ++mf) {
        aRe[ii][mf] = (f32x4){0.f,0.f,0.f,0.f};
        aIm[ii][mf] = (f32x4){0.f,0.f,0.f,0.f};
      }

    for (int ks = 0; ks < KS; ++ks) {
      AU xf[4], yf[4];
#pragma unroll
      for (int mf = 0; mf < 4; ++mf) {
        const unsigned int base = (unsigned int)(mf*16 + r15) * RSTR + 16*ks + 4*g;
#pragma unroll
        for (int d2 = 0; d2 < 4; ++d2) {
          xf[mf].u[d2] = Xl[base + d2];
          yf[mf].u[d2] = Yl[base + d2];
        }
      }
#pragma unroll
      for (int ii = 0; ii < 3; ++ii) {
        const int fs = ((it0 + ii)*KS + ks)*64 + lane;
        BU ubr, ubi, ubn;
        ubr.u = bre[fs];
        ubi.u = bim[fs];
        ubn.u.x = ubi.u.x ^ 0x80008000u; ubn.u.y = ubi.u.y ^ 0x80008000u;
        ubn.u.z = ubi.u.z ^ 0x80008000u; ubn.u.w = ubi.u.w ^ 0x80008000u;
#pragma unroll
        for (int mf = 0; mf < 4; ++mf) {
          // Wre = X*Hre - Y*Him ; Wim = X*Him + Y*Hre
          aRe[ii][mf] = __builtin_amdgcn_mfma_f32_16x16x32_bf16(xf[mf].v, ubr.v, aRe[ii][mf], 0, 0, 0);
          aRe[ii][mf] = __builtin_amdgcn_mfma_f32_16x16x32_bf16(yf[mf].v, ubn.v, aRe[ii][mf], 0, 0, 0);
          aIm[ii][mf] = __builtin_amdgcn_mfma_f32_16x16x32_bf16(xf[mf].v, ubi.v, aIm[ii][mf], 0, 0, 0);
          aIm[ii][mf] = __builtin_amdgcn_mfma_f32_16x16x32_bf16(yf[mf].v, ubr.v, aIm[ii][mf], 0, 0, 0);
        }
      }
    }

    // ---- fused epilogue for this i-group: quad_b += x*Wre + y*Wim ----
#pragma unroll
    for (int ii = 0; ii < 3; ++ii) {
      const int it = it0 + ii;
      const int dwi  = it*8 + (r15 >> 1);   // dword index of i = it*16 + r15
      const int hsel = r15 & 1;
#pragma unroll
      for (int mf = 0; mf < 4; ++mf) {
#pragma unroll
        for (int rr = 0; rr < 4; ++rr) {
          const int brow = mf*16 + 4*g + rr;          // D row = batch row
          const unsigned int px = Xl[(unsigned int)brow*RSTR + dwi];
          const unsigned int py = Yl[(unsigned int)brow*RSTR + dwi];
          p[mf][rr] += bfsel(px, hsel) * aRe[ii][mf][rr]
                     + bfsel(py, hsel) * aIm[ii][mf][rr];
        }
      }
    }
  }

  // ---- reduce over the 16 i-lanes ----
#pragma unroll
  for (int mf = 0; mf < 4; ++mf)
#pragma unroll
    for (int rr = 0; rr < 4; ++rr) {
      float v = p[mf][rr];
      v += __shfl_xor(v, 1);
      v += __shfl_xor(v, 2);
      v += __shfl_xor(v, 4);
      v += __shfl_xor(v, 8);
      p[mf][rr] = v;
    }

  if (r15 == 0) {
#pragma unroll
    for (int mf = 0; mf < 4; ++mf)
#pragma unroll
      for (int rr = 0; rr < 4; ++rr)
        qpart[wv][mf*16 + 4*g + rr] = p[mf][rr];
  }
  __syncthreads();
  if (t < ROWS) {
    const float quad = qpart[0][t] + qpart[1][t];
    out[bbase + t] = logf(quad + 1e-12f);
  }
}

// ---------------- host ----------------
extern "C" void kernel_launch(void* const* d_in, const int* in_sizes, int n_in,
                              void* d_out, int out_size, void* d_ws, size_t ws_size,
                              hipStream_t stream) {
  const float* q   = (const float*)d_in[0];
  const float* Lre = (const float*)d_in[1];
  const float* Lim = (const float*)d_in[2];
  float* out = (float*)d_out;
  uint4* bre = (uint4*)d_ws;
  uint4* bim = bre + NB;
  const int B = in_sizes[0] / 16;
  poskahler_prep<<<(NB + 255)/256, 256, 0, stream>>>(Lre, Lim, bre, bim);
  poskahler_main<<<B / ROWS, 128, 0, stream>>>(q, bre, bim, out);
}

// Round 3
// 65.767 us; speedup vs baseline: 17.8565x; 12.1240x over previous
//
#include <hip/hip_runtime.h>
#include <hip/hip_bf16.h>
#include <utility>

#define DEV static __device__ __forceinline__

typedef __attribute__((ext_vector_type(8))) short bf16x8;

constexpr int KM   = 165;          // number of monomials (deg<=3, 8 complex vars)
constexpr int IT   = 11;           // live i-tiles of 16 (165 -> 176)
constexpr int ITP  = 12;           // padded i-tile count (layout only)
constexpr int KS   = 6;            // k-steps of 32 -> 192 padded
constexpr int NB   = ITP * KS * 64;
constexpr int ROWS = 64;           // batch rows per block
constexpr int RSTR = 100;          // LDS row stride in dwords (96 used + 4 pad, 16B-aligned rows)

// ---------------- compile-time POWERS table (itertools.product order) ----------------
struct Pw { unsigned char p[8]; };
struct PwTab { Pw a[KM]; };
constexpr PwTab gen_powers() {
  PwTab t{};
  int idx = 0;
  for (int a0 = 0; a0 <= 3; ++a0)
  for (int a1 = 0; a1 <= 3-a0; ++a1)
  for (int a2 = 0; a2 <= 3-a0-a1; ++a2)
  for (int a3 = 0; a3 <= 3-a0-a1-a2; ++a3)
  for (int a4 = 0; a4 <= 3-a0-a1-a2-a3; ++a4)
  for (int a5 = 0; a5 <= 3-a0-a1-a2-a3-a4; ++a5)
  for (int a6 = 0; a6 <= 3-a0-a1-a2-a3-a4-a5; ++a6)
  for (int a7 = 0; a7 <= 3-a0-a1-a2-a3-a4-a5-a6; ++a7) {
    t.a[idx].p[0] = (unsigned char)a0; t.a[idx].p[1] = (unsigned char)a1;
    t.a[idx].p[2] = (unsigned char)a2; t.a[idx].p[3] = (unsigned char)a3;
    t.a[idx].p[4] = (unsigned char)a4; t.a[idx].p[5] = (unsigned char)a5;
    t.a[idx].p[6] = (unsigned char)a6; t.a[idx].p[7] = (unsigned char)a7;
    ++idx;
  }
  return t;
}
constexpr PwTab PW = gen_powers();

// ---------------- helpers ----------------
DEV unsigned int f2bf(float f) {            // RNE float -> bf16 bits
  unsigned int u = __builtin_bit_cast(unsigned int, f);
  u += 0x7fffu + ((u >> 16) & 1u);
  return u >> 16;
}
DEV unsigned int pack2(float lo, float hi) { return f2bf(lo) | (f2bf(hi) << 16); }
DEV float softplusf(float x) { return (x > 20.f) ? x : log1pf(expf(x)); }

// ---- monomial evaluation: ALL table indices are template params (scratch-proof) ----
template<int JJ, int C>
DEV void mono_step(float& r, float& i,
                   const float (&lx)[8][3], const float (&ly)[8][3]) {
  constexpr int pc = PW.a[JJ].p[C];
  if constexpr (pc > 0) {
    const float ar = lx[C][pc-1], ai = ly[C][pc-1];
    const float tr = r*ar - i*ai;
    i = r*ai + i*ar;
    r = tr;
  }
}
template<int JJ>
DEV void mono_eval(float& mr, float& mi,
                   const float (&lx)[8][3], const float (&ly)[8][3]) {
  float r = 1.f, i = 0.f;
  mono_step<JJ,0>(r,i,lx,ly); mono_step<JJ,1>(r,i,lx,ly);
  mono_step<JJ,2>(r,i,lx,ly); mono_step<JJ,3>(r,i,lx,ly);
  mono_step<JJ,4>(r,i,lx,ly); mono_step<JJ,5>(r,i,lx,ly);
  mono_step<JJ,6>(r,i,lx,ly); mono_step<JJ,7>(r,i,lx,ly);
  mr = r; mi = i;
}
template<int D>
DEV void gen_one(const float (&lx)[8][3], const float (&ly)[8][3],
                 unsigned int* Xl, unsigned int* Yl, unsigned int rb) {
  float r0 = 0.f, i0 = 0.f, r1 = 0.f, i1 = 0.f;
  if constexpr (2*D < KM)     mono_eval<2*D>(r0, i0, lx, ly);
  if constexpr (2*D + 1 < KM) mono_eval<2*D + 1>(r1, i1, lx, ly);
  Xl[rb + D] = pack2(r0, r1);
  Yl[rb + D] = pack2(i0, i1);
}
template<int W, int... Ds>
DEV void gen_seq(std::integer_sequence<int, Ds...>,
                 const float (&lx)[8][3], const float (&ly)[8][3],
                 unsigned int* Xl, unsigned int* Yl, unsigned int rb) {
  (gen_one<24*W + Ds>(lx, ly, Xl, Yl, rb), ...);
}
template<int W>
DEV void gen_wave(const float (&lx)[8][3], const float (&ly)[8][3],
                  unsigned int* Xl, unsigned int* Yl, unsigned int rb) {
  gen_seq<W>(std::make_integer_sequence<int, 24>{}, lx, ly, Xl, Yl, rb);
}

// ---------------- prep: conj(L)^T -> bf16 B-operand fragments (triangular) ----------
// fragment slot fs=(it*KS+ks)*64+lane holds B[k=i][col=j], j=it*16+(lane&15),
// i=ks*32+8*(lane>>4)+e ; value = conj(Ltilde[i,j]) (lower-tri + softplus diag)
__global__ void __launch_bounds__(256) poskahler_prep(
    const float* __restrict__ Lre, const float* __restrict__ Lim,
    uint4* __restrict__ bp, uint4* __restrict__ bq) {
  const int tid = blockIdx.x * 256 + threadIdx.x;
  if (tid >= NB) return;
  const int lane = tid & 63;
  const int it = (tid >> 6) / KS;
  const int ks = (tid >> 6) % KS;
  const int j  = it * 16 + (lane & 15);
  const int ib = ks * 32 + ((lane >> 4) << 3);
  float pr[8], qr[8];
#pragma unroll
  for (int e = 0; e < 8; ++e) { pr[e] = 0.f; qr[e] = 0.f; }
  if (j < KM) {
#pragma unroll
    for (int e = 0; e < 8; ++e) {
      const int i = ib + e;
      if (i < KM) {
        if (i > j)      { pr[e] = Lre[i*KM + j]; qr[e] = -Lim[i*KM + j]; }
        else if (i == j){ pr[e] = softplusf(Lre[j*KM + j]) + 0.001f; }
      }
    }
  }
  uint4 up, uq;
  up.x = pack2(pr[0], pr[1]); up.y = pack2(pr[2], pr[3]);
  up.z = pack2(pr[4], pr[5]); up.w = pack2(pr[6], pr[7]);
  uq.x = pack2(qr[0], qr[1]); uq.y = pack2(qr[2], qr[3]);
  uq.z = pack2(qr[4], qr[5]); uq.w = pack2(qr[6], qr[7]);
  bp[tid] = up;
  bq[tid] = uq;
}

// ---------------- main: monomials -> w = L^H z via MFMA -> log(|w|^2) --------------
__global__ void __launch_bounds__(256, 2) poskahler_main(
    const float* __restrict__ q,
    const uint4* __restrict__ bp, const uint4* __restrict__ bq,
    float* __restrict__ out) {
  __shared__ __align__(16) unsigned int Xl[ROWS * RSTR];  // Re(monomials) bf16-pairs
  __shared__ __align__(16) unsigned int Yl[ROWS * RSTR];  // Im(monomials)
  __shared__ float qpart[4][ROWS];

  const int t     = threadIdx.x;
  const int lane  = t & 63;
  const int wv    = t >> 6;                 // 4 waves
  const int bbase = blockIdx.x * ROWS;

  // ---- monomial generation: wave wv writes dwords [24wv, 24wv+24) for all 64 rows --
  {
    const float* qr = q + (size_t)(bbase + lane) * 16;
    const float4 q0 = ((const float4*)qr)[0];
    const float4 q1 = ((const float4*)qr)[1];
    const float4 q2 = ((const float4*)qr)[2];
    const float4 q3 = ((const float4*)qr)[3];
    const float xs[8] = {q0.x,q0.y,q0.z,q0.w,q1.x,q1.y,q1.z,q1.w};
    const float ys[8] = {q2.x,q2.y,q2.z,q2.w,q3.x,q3.y,q3.z,q3.w};
    float lx[8][3], ly[8][3];
#pragma unroll
    for (int c = 0; c < 8; ++c) {
      const float xr = xs[c], yi = ys[c];
      lx[c][0] = xr;             ly[c][0] = yi;
      lx[c][1] = xr*xr - yi*yi;  ly[c][1] = 2.f*xr*yi;
      lx[c][2] = lx[c][1]*xr - ly[c][1]*yi;
      ly[c][2] = lx[c][1]*yi + ly[c][1]*xr;
    }
    const unsigned int rb = (unsigned int)lane * RSTR;
    switch (wv) {
      case 0: gen_wave<0>(lx, ly, Xl, Yl, rb); break;
      case 1: gen_wave<1>(lx, ly, Xl, Yl, rb); break;
      case 2: gen_wave<2>(lx, ly, Xl, Yl, rb); break;
      default: gen_wave<3>(lx, ly, Xl, Yl, rb); break;
    }
  }
  __syncthreads();

  // ---- w = L^H z : per wave 3 interleaved i-tiles (it = 4*ii + wv) ----
  const int g   = lane >> 4;
  const int r15 = lane & 15;

  float aRe[3][4][4], aIm[3][4][4];
#pragma unroll
  for (int ii = 0; ii < 3; ++ii)
#pragma unroll
    for (int mf = 0; mf < 4; ++mf)
#pragma unroll
      for (int rr = 0; rr < 4; ++rr) { aRe[ii][mf][rr] = 0.f; aIm[ii][mf][rr] = 0.f; }

#pragma unroll 1
  for (int ks = 0; ks < KS; ++ks) {
    bf16x8 xf[4], yf[4];
#pragma unroll
    for (int mf = 0; mf < 4; ++mf) {
      const unsigned int base = (unsigned int)(mf*16 + r15) * RSTR + 16*ks + 4*g;
      xf[mf] = __builtin_bit_cast(bf16x8, *(const uint4*)&Xl[base]);
      yf[mf] = __builtin_bit_cast(bf16x8, *(const uint4*)&Yl[base]);
    }
#pragma unroll
    for (int ii = 0; ii < 3; ++ii) {
      const int it = 4*ii + wv;
      // tile (it,ks) of the upper-tri L^H is nonzero iff 32ks+31 >= 16it, and it<IT
      if (it <= 2*ks + 1 && it < IT) {
        const int fs = (it*KS + ks)*64 + lane;
        const uint4 up = bp[fs];
        const uint4 uq = bq[fs];
        uint4 un;
        un.x = uq.x ^ 0x80008000u; un.y = uq.y ^ 0x80008000u;
        un.z = uq.z ^ 0x80008000u; un.w = uq.w ^ 0x80008000u;
        const bf16x8 vp = __builtin_bit_cast(bf16x8, up);
        const bf16x8 vq = __builtin_bit_cast(bf16x8, uq);
        const bf16x8 vn = __builtin_bit_cast(bf16x8, un);
#pragma unroll
        for (int mf = 0; mf < 4; ++mf) {
          // wre = P x + Q y ; wim = P y - Q x
          typedef __attribute__((ext_vector_type(4))) float f4;
          f4 cre = { aRe[ii][mf][0], aRe[ii][mf][1], aRe[ii][mf][2], aRe[ii][mf][3] };
          f4 cim = { aIm[ii][mf][0], aIm[ii][mf][1], aIm[ii][mf][2], aIm[ii][mf][3] };
          cre = __builtin_amdgcn_mfma_f32_16x16x32_bf16(xf[mf], vp, cre, 0, 0, 0);
          cre = __builtin_amdgcn_mfma_f32_16x16x32_bf16(yf[mf], vq, cre, 0, 0, 0);
          cim = __builtin_amdgcn_mfma_f32_16x16x32_bf16(yf[mf], vp, cim, 0, 0, 0);
          cim = __builtin_amdgcn_mfma_f32_16x16x32_bf16(xf[mf], vn, cim, 0, 0, 0);
#pragma unroll
          for (int rr = 0; rr < 4; ++rr) { aRe[ii][mf][rr] = cre[rr]; aIm[ii][mf][rr] = cim[rr]; }
        }
      }
    }
  }

  // ---- epilogue: quad partial = sum_j |w_j|^2 (no LDS re-read) ----
  float p[4][4];
#pragma unroll
  for (int mf = 0; mf < 4; ++mf)
#pragma unroll
    for (int rr = 0; rr < 4; ++rr) p[mf][rr] = 0.f;

#pragma unroll
  for (int ii = 0; ii < 3; ++ii)
#pragma unroll
    for (int mf = 0; mf < 4; ++mf)
#pragma unroll
      for (int rr = 0; rr < 4; ++rr)
        p[mf][rr] += aRe[ii][mf][rr]*aRe[ii][mf][rr] + aIm[ii][mf][rr]*aIm[ii][mf][rr];

#pragma unroll
  for (int mf = 0; mf < 4; ++mf)
#pragma unroll
    for (int rr = 0; rr < 4; ++rr) {
      float v = p[mf][rr];
      v += __shfl_xor(v, 1);
      v += __shfl_xor(v, 2);
      v += __shfl_xor(v, 4);
      v += __shfl_xor(v, 8);
      p[mf][rr] = v;
    }

  if (r15 == 0) {
#pragma unroll
    for (int mf = 0; mf < 4; ++mf)
#pragma unroll
      for (int rr = 0; rr < 4; ++rr)
        qpart[wv][mf*16 + 4*g + rr] = p[mf][rr];
  }
  __syncthreads();
  if (t < ROWS) {
    const float quad = qpart[0][t] + qpart[1][t] + qpart[2][t] + qpart[3][t];
    out[bbase + t] = logf(quad + 1e-12f);
  }
}

// ---------------- host ----------------
extern "C" void kernel_launch(void* const* d_in, const int* in_sizes, int n_in,
                              void* d_out, int out_size, void* d_ws, size_t ws_size,
                              hipStream_t stream) {
  const float* q   = (const float*)d_in[0];
  const float* Lre = (const float*)d_in[1];
  const float* Lim = (const float*)d_in[2];
  float* out = (float*)d_out;
  uint4* bp = (uint4*)d_ws;
  uint4* bq = bp + NB;
  const int B = in_sizes[0] / 16;
  poskahler_prep<<<(NB + 255)/256, 256, 0, stream>>>(Lre, Lim, bp, bq);
  poskahler_main<<<B / ROWS, 256, 0, stream>>>(q, bp, bq, out);
}

// Round 4
// 56.855 us; speedup vs baseline: 20.6556x; 1.1568x over previous
//
#include <hip/hip_runtime.h>
#include <hip/hip_bf16.h>
#include <utility>

#define DEV static __device__ __forceinline__

typedef __attribute__((ext_vector_type(8))) short bf16x8;
typedef __attribute__((ext_vector_type(4))) float f32x4;

constexpr int KM   = 165;          // number of monomials (deg<=3, 8 complex vars)
constexpr int IT   = 11;           // live i-tiles of 16 (165 -> 176)
constexpr int ITP  = 12;           // padded i-tile count (B layout only)
constexpr int KS   = 6;            // k-steps of 32 -> 192 padded
constexpr int NB   = ITP * KS * 64;
constexpr int ROWS = 64;           // batch rows per block

// ---------------- compile-time POWERS table (itertools.product order) ----------------
struct Pw { unsigned char p[8]; };
struct PwTab { Pw a[KM]; };
constexpr PwTab gen_powers() {
  PwTab t{};
  int idx = 0;
  for (int a0 = 0; a0 <= 3; ++a0)
  for (int a1 = 0; a1 <= 3-a0; ++a1)
  for (int a2 = 0; a2 <= 3-a0-a1; ++a2)
  for (int a3 = 0; a3 <= 3-a0-a1-a2; ++a3)
  for (int a4 = 0; a4 <= 3-a0-a1-a2-a3; ++a4)
  for (int a5 = 0; a5 <= 3-a0-a1-a2-a3-a4; ++a5)
  for (int a6 = 0; a6 <= 3-a0-a1-a2-a3-a4-a5; ++a6)
  for (int a7 = 0; a7 <= 3-a0-a1-a2-a3-a4-a5-a6; ++a7) {
    t.a[idx].p[0] = (unsigned char)a0; t.a[idx].p[1] = (unsigned char)a1;
    t.a[idx].p[2] = (unsigned char)a2; t.a[idx].p[3] = (unsigned char)a3;
    t.a[idx].p[4] = (unsigned char)a4; t.a[idx].p[5] = (unsigned char)a5;
    t.a[idx].p[6] = (unsigned char)a6; t.a[idx].p[7] = (unsigned char)a7;
    ++idx;
  }
  return t;
}
constexpr PwTab PW = gen_powers();

// ---------------- helpers ----------------
DEV unsigned int f2bf(float f) {            // RNE float -> bf16 bits
  unsigned int u = __builtin_bit_cast(unsigned int, f);
  u += 0x7fffu + ((u >> 16) & 1u);
  return u >> 16;
}
DEV unsigned int pack2(float lo, float hi) { return f2bf(lo) | (f2bf(hi) << 16); }
DEV float softplusf(float x) { return (x > 20.f) ? x : log1pf(expf(x)); }

// ---- monomial evaluation: ALL table indices are template params (scratch-proof) ----
template<int JJ, int C>
DEV void mono_step(float& r, float& i,
                   const float (&lx)[8][3], const float (&ly)[8][3]) {
  constexpr int pc = PW.a[JJ].p[C];
  if constexpr (pc > 0) {
    const float ar = lx[C][pc-1], ai = ly[C][pc-1];
    const float tr = r*ar - i*ai;
    i = r*ai + i*ar;
    r = tr;
  }
}
template<int JJ>
DEV void mono_eval(float& mr, float& mi,
                   const float (&lx)[8][3], const float (&ly)[8][3]) {
  float r = 1.f, i = 0.f;
  mono_step<JJ,0>(r,i,lx,ly); mono_step<JJ,1>(r,i,lx,ly);
  mono_step<JJ,2>(r,i,lx,ly); mono_step<JJ,3>(r,i,lx,ly);
  mono_step<JJ,4>(r,i,lx,ly); mono_step<JJ,5>(r,i,lx,ly);
  mono_step<JJ,6>(r,i,lx,ly); mono_step<JJ,7>(r,i,lx,ly);
  mr = r; mi = i;
}
template<int JJ>
DEV void mono_eval_guard(float& r, float& i,
                         const float (&lx)[8][3], const float (&ly)[8][3]) {
  if constexpr (JJ < KM) mono_eval<JJ>(r, i, lx, ly);
  else { r = 0.f; i = 0.f; }
}

// ---- gen: chunk T covers monomials [8T, 8T+8) = k-slice (ks=T>>2, g=T&3) ----
template<int T, int... Us>
DEV void gen8(std::integer_sequence<int, Us...>, float (&mr)[8], float (&mi)[8],
              const float (&lx)[8][3], const float (&ly)[8][3]) {
  (mono_eval_guard<8*T + Us>(mr[Us], mi[Us], lx, ly), ...);
}
template<int T>
DEV void gen_chunk(const float (&lx)[8][3], const float (&ly)[8][3],
                   unsigned int* Xf, unsigned int* Yf, int mf, int r15) {
  constexpr int ksv = T >> 2;
  constexpr int gv  = T & 3;
  float mr[8], mi[8];
  gen8<T>(std::make_integer_sequence<int, 8>{}, mr, mi, lx, ly);
  uint4 ux, uy;
  ux.x = pack2(mr[0], mr[1]); ux.y = pack2(mr[2], mr[3]);
  ux.z = pack2(mr[4], mr[5]); ux.w = pack2(mr[6], mr[7]);
  uy.x = pack2(mi[0], mi[1]); uy.y = pack2(mi[2], mi[3]);
  uy.z = pack2(mi[4], mi[5]); uy.w = pack2(mi[6], mi[7]);
  const unsigned int off = (unsigned int)((mf*6 + ksv)*256 + gv*64 + r15*4);
  *(uint4*)&Xf[off] = ux;
  *(uint4*)&Yf[off] = uy;
}
template<int W, int... Ts>
DEV void gen_seq(std::integer_sequence<int, Ts...>,
                 const float (&lx)[8][3], const float (&ly)[8][3],
                 unsigned int* Xf, unsigned int* Yf, int mf, int r15) {
  (gen_chunk<6*W + Ts>(lx, ly, Xf, Yf, mf, r15), ...);
}
template<int W>
DEV void gen_wave(const float (&lx)[8][3], const float (&ly)[8][3],
                  unsigned int* Xf, unsigned int* Yf, int mf, int r15) {
  gen_seq<W>(std::make_integer_sequence<int, 6>{}, lx, ly, Xf, Yf, mf, r15);
}

// ---------------- prep: conj(L)^T -> bf16 B-operand fragments (triangular) ----------
__global__ void __launch_bounds__(256) poskahler_prep(
    const float* __restrict__ Lre, const float* __restrict__ Lim,
    uint4* __restrict__ bp, uint4* __restrict__ bq) {
  const int tid = blockIdx.x * 256 + threadIdx.x;
  if (tid >= NB) return;
  const int lane = tid & 63;
  const int it = (tid >> 6) / KS;
  const int ks = (tid >> 6) % KS;
  const int j  = it * 16 + (lane & 15);
  const int ib = ks * 32 + ((lane >> 4) << 3);
  float pr[8], qr[8];
#pragma unroll
  for (int e = 0; e < 8; ++e) { pr[e] = 0.f; qr[e] = 0.f; }
  if (j < KM) {
#pragma unroll
    for (int e = 0; e < 8; ++e) {
      const int i = ib + e;
      if (i < KM) {
        if (i > j)      { pr[e] = Lre[i*KM + j]; qr[e] = -Lim[i*KM + j]; }
        else if (i == j){ pr[e] = softplusf(Lre[j*KM + j]) + 0.001f; }
      }
    }
  }
  uint4 up, uq;
  up.x = pack2(pr[0], pr[1]); up.y = pack2(pr[2], pr[3]);
  up.z = pack2(pr[4], pr[5]); up.w = pack2(pr[6], pr[7]);
  uq.x = pack2(qr[0], qr[1]); uq.y = pack2(qr[2], qr[3]);
  uq.z = pack2(qr[4], qr[5]); uq.w = pack2(qr[6], qr[7]);
  bp[tid] = up;
  bq[tid] = uq;
}

// ---------------- main k-loop building blocks (fully static) ----------------
template<int KSv>
DEV void load_tiles(const uint4* __restrict__ bp, const uint4* __restrict__ bq,
                    int wv, int lane, uint4 (&tp)[3], uint4 (&tq)[3]) {
#pragma unroll
  for (int ii = 0; ii < 3; ++ii) {
    const int it = 4*ii + wv;
    if (it <= 2*KSv + 1 && it < IT) {
      const int fs = (it*KS + KSv)*64 + lane;
      tp[ii] = bp[fs];
      tq[ii] = bq[fs];
    }
  }
}

template<int KSv>
DEV void compute_ks(const unsigned int* Xf, const unsigned int* Yf,
                    int wv, int lane,
                    const uint4 (&tp)[3], const uint4 (&tq)[3],
                    float (&aRe)[3][4][4], float (&aIm)[3][4][4]) {
  bf16x8 xf[4], yf[4];
#pragma unroll
  for (int mf = 0; mf < 4; ++mf) {
    const unsigned int off = (unsigned int)((mf*6 + KSv)*256 + lane*4);
    xf[mf] = __builtin_bit_cast(bf16x8, *(const uint4*)&Xf[off]);
    yf[mf] = __builtin_bit_cast(bf16x8, *(const uint4*)&Yf[off]);
  }
#pragma unroll
  for (int ii = 0; ii < 3; ++ii) {
    const int it = 4*ii + wv;
    if (it <= 2*KSv + 1 && it < IT) {
      const uint4 up = tp[ii];
      const uint4 uq = tq[ii];
      uint4 un;
      un.x = uq.x ^ 0x80008000u; un.y = uq.y ^ 0x80008000u;
      un.z = uq.z ^ 0x80008000u; un.w = uq.w ^ 0x80008000u;
      const bf16x8 vp = __builtin_bit_cast(bf16x8, up);
      const bf16x8 vq = __builtin_bit_cast(bf16x8, uq);
      const bf16x8 vn = __builtin_bit_cast(bf16x8, un);
#pragma unroll
      for (int mf = 0; mf < 4; ++mf) {
        f32x4 cre = { aRe[ii][mf][0], aRe[ii][mf][1], aRe[ii][mf][2], aRe[ii][mf][3] };
        f32x4 cim = { aIm[ii][mf][0], aIm[ii][mf][1], aIm[ii][mf][2], aIm[ii][mf][3] };
        // wre = P x + Q y ; wim = P y - Q x
        cre = __builtin_amdgcn_mfma_f32_16x16x32_bf16(xf[mf], vp, cre, 0, 0, 0);
        cre = __builtin_amdgcn_mfma_f32_16x16x32_bf16(yf[mf], vq, cre, 0, 0, 0);
        cim = __builtin_amdgcn_mfma_f32_16x16x32_bf16(yf[mf], vp, cim, 0, 0, 0);
        cim = __builtin_amdgcn_mfma_f32_16x16x32_bf16(xf[mf], vn, cim, 0, 0, 0);
#pragma unroll
        for (int rr = 0; rr < 4; ++rr) { aRe[ii][mf][rr] = cre[rr]; aIm[ii][mf][rr] = cim[rr]; }
      }
    }
  }
}

// ---------------- main: monomials -> w = L^H z via MFMA -> log(|w|^2) --------------
__global__ void __launch_bounds__(256, 2) poskahler_main(
    const float* __restrict__ q,
    const uint4* __restrict__ bp, const uint4* __restrict__ bq,
    float* __restrict__ out) {
  // fragment-ordered monomial store: region (mf*6+ks)*256 dwords, lane entry lane*4
  __shared__ __align__(16) unsigned int Xf[6144];
  __shared__ __align__(16) unsigned int Yf[6144];
  __shared__ float qpart[4][ROWS];

  const int t     = threadIdx.x;
  const int lane  = t & 63;
  const int wv    = t >> 6;                 // 4 waves
  const int bbase = blockIdx.x * ROWS;
  const int mf_r  = lane >> 4;              // this thread's row -> frag mf
  const int r15   = lane & 15;

  // ---- B-tile prefetch for ks=0,1 (latency hides under gen phase) ----
  uint4 tpA[3] = {}, tqA[3] = {}, tpB[3] = {}, tqB[3] = {};
  load_tiles<0>(bp, bq, wv, lane, tpA, tqA);
  load_tiles<1>(bp, bq, wv, lane, tpB, tqB);

  // ---- monomial generation: wave wv covers monomials [48wv, 48wv+48) of each row --
  {
    const float* qr = q + (size_t)(bbase + lane) * 16;
    const float4 q0 = ((const float4*)qr)[0];
    const float4 q1 = ((const float4*)qr)[1];
    const float4 q2 = ((const float4*)qr)[2];
    const float4 q3 = ((const float4*)qr)[3];
    const float xs[8] = {q0.x,q0.y,q0.z,q0.w,q1.x,q1.y,q1.z,q1.w};
    const float ys[8] = {q2.x,q2.y,q2.z,q2.w,q3.x,q3.y,q3.z,q3.w};
    float lx[8][3], ly[8][3];
#pragma unroll
    for (int c = 0; c < 8; ++c) {
      const float xr = xs[c], yi = ys[c];
      lx[c][0] = xr;             ly[c][0] = yi;
      lx[c][1] = xr*xr - yi*yi;  ly[c][1] = 2.f*xr*yi;
      lx[c][2] = lx[c][1]*xr - ly[c][1]*yi;
      ly[c][2] = lx[c][1]*yi + ly[c][1]*xr;
    }
    switch (wv) {
      case 0: gen_wave<0>(lx, ly, Xf, Yf, mf_r, r15); break;
      case 1: gen_wave<1>(lx, ly, Xf, Yf, mf_r, r15); break;
      case 2: gen_wave<2>(lx, ly, Xf, Yf, mf_r, r15); break;
      default: gen_wave<3>(lx, ly, Xf, Yf, mf_r, r15); break;
    }
  }
  __syncthreads();

  // ---- w = L^H z : ks fully unrolled, double-buffered B tiles ----
  float aRe[3][4][4], aIm[3][4][4];
#pragma unroll
  for (int ii = 0; ii < 3; ++ii)
#pragma unroll
    for (int mf = 0; mf < 4; ++mf)
#pragma unroll
      for (int rr = 0; rr < 4; ++rr) { aRe[ii][mf][rr] = 0.f; aIm[ii][mf][rr] = 0.f; }

  compute_ks<0>(Xf, Yf, wv, lane, tpA, tqA, aRe, aIm);
  load_tiles<2>(bp, bq, wv, lane, tpA, tqA);
  compute_ks<1>(Xf, Yf, wv, lane, tpB, tqB, aRe, aIm);
  load_tiles<3>(bp, bq, wv, lane, tpB, tqB);
  compute_ks<2>(Xf, Yf, wv, lane, tpA, tqA, aRe, aIm);
  load_tiles<4>(bp, bq, wv, lane, tpA, tqA);
  compute_ks<3>(Xf, Yf, wv, lane, tpB, tqB, aRe, aIm);
  load_tiles<5>(bp, bq, wv, lane, tpB, tqB);
  compute_ks<4>(Xf, Yf, wv, lane, tpA, tqA, aRe, aIm);
  compute_ks<5>(Xf, Yf, wv, lane, tpB, tqB, aRe, aIm);

  // ---- epilogue: quad partial = sum_j |w_j|^2 ----
  float p[4][4];
#pragma unroll
  for (int mf = 0; mf < 4; ++mf)
#pragma unroll
    for (int rr = 0; rr < 4; ++rr) p[mf][rr] = 0.f;

#pragma unroll
  for (int ii = 0; ii < 3; ++ii)
#pragma unroll
    for (int mf = 0; mf < 4; ++mf)
#pragma unroll
      for (int rr = 0; rr < 4; ++rr)
        p[mf][rr] += aRe[ii][mf][rr]*aRe[ii][mf][rr] + aIm[ii][mf][rr]*aIm[ii][mf][rr];

#pragma unroll
  for (int mf = 0; mf < 4; ++mf)
#pragma unroll
    for (int rr = 0; rr < 4; ++rr) {
      float v = p[mf][rr];
      v += __shfl_xor(v, 1);
      v += __shfl_xor(v, 2);
      v += __shfl_xor(v, 4);
      v += __shfl_xor(v, 8);
      p[mf][rr] = v;
    }

  if (r15 == 0) {
#pragma unroll
    for (int mf = 0; mf < 4; ++mf)
#pragma unroll
      for (int rr = 0; rr < 4; ++rr)
        qpart[wv][mf*16 + 4*(lane >> 4) + rr] = p[mf][rr];
  }
  __syncthreads();
  if (t < ROWS) {
    const float quad = qpart[0][t] + qpart[1][t] + qpart[2][t] + qpart[3][t];
    out[bbase + t] = logf(quad + 1e-12f);
  }
}

// ---------------- host ----------------
extern "C" void kernel_launch(void* const* d_in, const int* in_sizes, int n_in,
                              void* d_out, int out_size, void* d_ws, size_t ws_size,
                              hipStream_t stream) {
  const float* q   = (const float*)d_in[0];
  const float* Lre = (const float*)d_in[1];
  const float* Lim = (const float*)d_in[2];
  float* out = (float*)d_out;
  uint4* bp = (uint4*)d_ws;
  uint4* bq = bp + NB;
  const int B = in_sizes[0] / 16;
  poskahler_prep<<<(NB + 255)/256, 256, 0, stream>>>(Lre, Lim, bp, bq);
  poskahler_main<<<B / ROWS, 256, 0, stream>>>(q, bp, bq, out);
}